// Round 1
// baseline (147.423 us; speedup 1.0000x reference)
//
#include <hip/hip_runtime.h>
#include <stdint.h>

#define NDIM 8192
#define DDIM 256
#define CAP  2048   // candidate capacity (power of 2)
#define MAXK 64

// Map float bits to an unsigned key with the same total order.
__device__ inline uint32_t f2key(float f) {
    uint32_t u = __float_as_uint(f);
    return (u & 0x80000000u) ? ~u : (u | 0x80000000u);
}

__global__ __launch_bounds__(256) void topk_agg_kernel(
    const float* __restrict__ A, const float* __restrict__ X,
    const float* __restrict__ alpha_p, const int* __restrict__ k_p,
    float* __restrict__ out)
{
    const int row  = blockIdx.x;
    const int tid  = threadIdx.x;
    const int lane = tid & 63;
    const int wid  = tid >> 6;

    __shared__ unsigned long long cand[CAP];
    __shared__ int s_count;
    __shared__ int s_sel[MAXK];
    __shared__ unsigned long long s_red[4];

    int k = *k_p;
    if (k > MAXK) k = MAXK;           // defensive clamp (k==32 here)
    const float alpha = *alpha_p;

    const float* __restrict__ rowp = A + (size_t)row * NDIM;

    // ---- Phase 1: collect candidates above a threshold ----------------
    const float thrs[6] = {2.0f, 3.0f, 4.5f, 1.2f, 0.0f, -1.5f};
    bool ok = false;
    int count = 0;

    for (int ti = 0; ti < 6 && !ok; ++ti) {
        const float thr = thrs[ti];
        if (tid == 0) s_count = 0;
        __syncthreads();

        // 8192 elems / 256 threads = 32 floats = 8 float4 per thread
        for (int it = 0; it < 8; ++it) {
            const int base = (it * 256 + tid) * 4;
            const float4 v = *reinterpret_cast<const float4*>(rowp + base);
            #pragma unroll
            for (int c = 0; c < 4; ++c) {
                const float f = (c == 0) ? v.x : (c == 1) ? v.y : (c == 2) ? v.z : v.w;
                const bool pred = f > thr;
                const unsigned long long mask = __ballot(pred);
                if (mask) {
                    const int leader = __ffsll((unsigned long long)mask) - 1;
                    int basec = 0;
                    if (lane == leader)
                        basec = atomicAdd(&s_count, __popcll(mask));
                    basec = __shfl(basec, leader, 64);
                    if (pred) {
                        const int off = basec +
                            __popcll(mask & ((1ull << lane) - 1ull));
                        if (off < CAP) {
                            const int idx = base + c;
                            const unsigned long long comp =
                                ((unsigned long long)f2key(f) << 32) |
                                (uint32_t)(~(uint32_t)idx);
                            cand[off] = comp;
                        }
                    }
                }
            }
        }
        __syncthreads();
        count = s_count;               // uniform across block
        ok = (count >= k && count <= CAP);
        __syncthreads();               // protect s_count reset next iter
    }

    // ---- Phase 2: select top-k indices --------------------------------
    if (ok) {
        // pad to next pow2 and bitonic-sort descending
        int npow2 = 2;
        while (npow2 < count) npow2 <<= 1;
        for (int i = tid; i < npow2; i += 256)
            if (i >= count) cand[i] = 0ull;

        for (int size = 2; size <= npow2; size <<= 1) {
            for (int stride = size >> 1; stride > 0; stride >>= 1) {
                __syncthreads();
                for (int i = tid; i < npow2; i += 256) {
                    const int j = i ^ stride;
                    if (j > i) {
                        const unsigned long long a = cand[i];
                        const unsigned long long b = cand[j];
                        const bool desc = ((i & size) == 0);
                        if (desc ? (a < b) : (a > b)) {
                            cand[i] = b;
                            cand[j] = a;
                        }
                    }
                }
            }
        }
        __syncthreads();
        if (tid < k)
            s_sel[tid] = (int)(~(uint32_t)(cand[tid] & 0xFFFFFFFFull));
        __syncthreads();
    } else {
        // exact (slow) fallback — never triggers for normal data
        for (int t = 0; t < k; ++t) {
            unsigned long long best = 0ull;
            for (int it = 0; it < NDIM / 256; ++it) {
                const int idx = it * 256 + tid;
                const float f = rowp[idx];
                bool taken = false;
                for (int s = 0; s < t; ++s) taken |= (s_sel[s] == idx);
                if (!taken) {
                    const unsigned long long comp =
                        ((unsigned long long)f2key(f) << 32) |
                        (uint32_t)(~(uint32_t)idx);
                    if (comp > best) best = comp;
                }
            }
            #pragma unroll
            for (int o = 32; o > 0; o >>= 1) {
                const unsigned long long other = __shfl_down(best, o, 64);
                if (other > best) best = other;
            }
            if (lane == 0) s_red[wid] = best;
            __syncthreads();
            if (tid == 0) {
                unsigned long long b = s_red[0];
                for (int w = 1; w < 4; ++w)
                    if (s_red[w] > b) b = s_red[w];
                s_sel[t] = (int)(~(uint32_t)(b & 0xFFFFFFFFull));
            }
            __syncthreads();
        }
    }

    // ---- Phase 3: gather + residual -----------------------------------
    // tid == column d (DDIM == 256 == blockDim.x)
    float acc = 0.0f;
    for (int t = 0; t < k; ++t) {
        acc += X[(size_t)s_sel[t] * DDIM + tid];
    }
    const size_t o = (size_t)row * DDIM + tid;
    out[o] = X[o] + alpha * acc;
}

extern "C" void kernel_launch(void* const* d_in, const int* in_sizes, int n_in,
                              void* d_out, int out_size, void* d_ws, size_t ws_size,
                              hipStream_t stream) {
    const float* A     = (const float*)d_in[0];
    const float* X     = (const float*)d_in[1];
    const float* alpha = (const float*)d_in[2];
    const int*   k     = (const int*)d_in[3];
    float* out = (float*)d_out;

    topk_agg_kernel<<<NDIM, 256, 0, stream>>>(A, X, alpha, k, out);
}

// Round 2
// 141.661 us; speedup vs baseline: 1.0407x; 1.0407x over previous
//
#include <hip/hip_runtime.h>
#include <stdint.h>

#define NDIM 8192
#define DDIM 256
#define CAP  2048   // candidate capacity (power of 2)
#define MAXK 64

// Map float bits to an unsigned key with the same total order.
__device__ inline uint32_t f2key(float f) {
    uint32_t u = __float_as_uint(f);
    return (u & 0x80000000u) ? ~u : (u | 0x80000000u);
}

__global__ __launch_bounds__(256) void topk_agg_kernel(
    const float* __restrict__ A, const float* __restrict__ X,
    const float* __restrict__ alpha_p, const int* __restrict__ k_p,
    float* __restrict__ out)
{
    const int row  = blockIdx.x;
    const int tid  = threadIdx.x;
    const int lane = tid & 63;
    const int wid  = tid >> 6;

    __shared__ unsigned long long cand[CAP];
    __shared__ int s_count;
    __shared__ int s_sel[MAXK];
    __shared__ unsigned long long s_red[4];

    int k = *k_p;
    if (k > MAXK) k = MAXK;           // defensive clamp (k==32 here)
    const float alpha = *alpha_p;

    const float* __restrict__ rowp = A + (size_t)row * NDIM;

    // ---- Load the whole row into registers (8 independent float4) ----
    float4 v0, v1, v2, v3, v4, v5, v6, v7;
    {
        const float4* p = reinterpret_cast<const float4*>(rowp) ;
        v0 = p[0 * 256 + tid];
        v1 = p[1 * 256 + tid];
        v2 = p[2 * 256 + tid];
        v3 = p[3 * 256 + tid];
        v4 = p[4 * 256 + tid];
        v5 = p[5 * 256 + tid];
        v6 = p[6 * 256 + tid];
        v7 = p[7 * 256 + tid];
    }

    // ---- Phase 1: collect candidates above a threshold ----------------
    // Direct atomicAdd per matching element: matches are rare (~2% at 2.0),
    // so the common path is just a compare. Order in cand[] is racy but the
    // sort on unique keys makes the final result deterministic.
    const float thrs[6] = {2.0f, 3.0f, 4.5f, 1.2f, 0.0f, -1.5f};
    bool ok = false;
    int count = 0;

    for (int ti = 0; ti < 6 && !ok; ++ti) {
        const float thr = thrs[ti];
        if (tid == 0) s_count = 0;
        __syncthreads();

        #pragma unroll
        for (int i = 0; i < 8; ++i) {
            const float4 v = (i == 0) ? v0 : (i == 1) ? v1 : (i == 2) ? v2 :
                             (i == 3) ? v3 : (i == 4) ? v4 : (i == 5) ? v5 :
                             (i == 6) ? v6 : v7;
            const int base = (i * 256 + tid) * 4;
            #pragma unroll
            for (int c = 0; c < 4; ++c) {
                const float f = (c == 0) ? v.x : (c == 1) ? v.y :
                                (c == 2) ? v.z : v.w;
                if (f > thr) {
                    const int pos = atomicAdd(&s_count, 1);
                    if (pos < CAP) {
                        const int idx = base + c;
                        cand[pos] = ((unsigned long long)f2key(f) << 32) |
                                    (uint32_t)(~(uint32_t)idx);
                    }
                }
            }
        }
        __syncthreads();
        count = s_count;               // uniform across block
        ok = (count >= k && count <= CAP);
        __syncthreads();               // protect s_count reset next iter
    }

    // ---- Phase 2: select top-k indices --------------------------------
    if (ok) {
        // pad to next pow2 and bitonic-sort descending
        int npow2 = 2;
        while (npow2 < count) npow2 <<= 1;
        for (int i = tid; i < npow2; i += 256)
            if (i >= count) cand[i] = 0ull;

        for (int size = 2; size <= npow2; size <<= 1) {
            for (int stride = size >> 1; stride > 0; stride >>= 1) {
                __syncthreads();
                for (int i = tid; i < npow2; i += 256) {
                    const int j = i ^ stride;
                    if (j > i) {
                        const unsigned long long a = cand[i];
                        const unsigned long long b = cand[j];
                        const bool desc = ((i & size) == 0);
                        if (desc ? (a < b) : (a > b)) {
                            cand[i] = b;
                            cand[j] = a;
                        }
                    }
                }
            }
        }
        __syncthreads();
        if (tid < k)
            s_sel[tid] = (int)(~(uint32_t)(cand[tid] & 0xFFFFFFFFull));
        __syncthreads();
    } else {
        // exact (slow) fallback — never triggers for normal data
        for (int t = 0; t < k; ++t) {
            unsigned long long best = 0ull;
            for (int it = 0; it < NDIM / 256; ++it) {
                const int idx = it * 256 + tid;
                const float f = rowp[idx];
                bool taken = false;
                for (int s = 0; s < t; ++s) taken |= (s_sel[s] == idx);
                if (!taken) {
                    const unsigned long long comp =
                        ((unsigned long long)f2key(f) << 32) |
                        (uint32_t)(~(uint32_t)idx);
                    if (comp > best) best = comp;
                }
            }
            #pragma unroll
            for (int o = 32; o > 0; o >>= 1) {
                const unsigned long long other = __shfl_down(best, o, 64);
                if (other > best) best = other;
            }
            if (lane == 0) s_red[wid] = best;
            __syncthreads();
            if (tid == 0) {
                unsigned long long b = s_red[0];
                for (int w = 1; w < 4; ++w)
                    if (s_red[w] > b) b = s_red[w];
                s_sel[t] = (int)(~(uint32_t)(b & 0xFFFFFFFFull));
            }
            __syncthreads();
        }
    }

    // ---- Phase 3: gather + residual -----------------------------------
    // tid == column d (DDIM == 256 == blockDim.x)
    float acc = 0.0f;
    for (int t = 0; t < k; ++t) {
        acc += X[(size_t)s_sel[t] * DDIM + tid];
    }
    const size_t o = (size_t)row * DDIM + tid;
    out[o] = X[o] + alpha * acc;
}

extern "C" void kernel_launch(void* const* d_in, const int* in_sizes, int n_in,
                              void* d_out, int out_size, void* d_ws, size_t ws_size,
                              hipStream_t stream) {
    const float* A     = (const float*)d_in[0];
    const float* X     = (const float*)d_in[1];
    const float* alpha = (const float*)d_in[2];
    const int*   k     = (const int*)d_in[3];
    float* out = (float*)d_out;

    topk_agg_kernel<<<NDIM, 256, 0, stream>>>(A, X, alpha, k, out);
}

// Round 3
// 76.126 us; speedup vs baseline: 1.9366x; 1.8609x over previous
//
#include <hip/hip_runtime.h>
#include <stdint.h>

#define NDIM 8192
#define DDIM 256
#define CAP  2048   // candidate capacity (power of 2)
#define MAXK 64

// Map float bits to an unsigned key with the same total order.
__device__ inline uint32_t f2key(float f) {
    uint32_t u = __float_as_uint(f);
    return (u & 0x80000000u) ? ~u : (u | 0x80000000u);
}

__global__ __launch_bounds__(256) void topk_agg_kernel(
    const float* __restrict__ A, const float* __restrict__ X,
    const float* __restrict__ alpha_p, const int* __restrict__ k_p,
    float* __restrict__ out)
{
    const int row  = blockIdx.x;
    const int tid  = threadIdx.x;
    const int lane = tid & 63;
    const int wid  = tid >> 6;

    __shared__ unsigned long long cand[CAP];
    __shared__ int s_count;
    __shared__ int s_sel[MAXK];
    __shared__ unsigned long long s_red[4];

    int k = *k_p;
    if (k > MAXK) k = MAXK;           // defensive clamp (k==32 here)
    const float alpha = *alpha_p;

    const float* __restrict__ rowp = A + (size_t)row * NDIM;

    // Prefetch the residual X value early (independent of selection).
    const float xres = X[(size_t)row * DDIM + tid];

    // ---- Load the whole row into registers (8 independent float4) ----
    float4 v0, v1, v2, v3, v4, v5, v6, v7;
    {
        const float4* p = reinterpret_cast<const float4*>(rowp);
        v0 = p[0 * 256 + tid];
        v1 = p[1 * 256 + tid];
        v2 = p[2 * 256 + tid];
        v3 = p[3 * 256 + tid];
        v4 = p[4 * 256 + tid];
        v5 = p[5 * 256 + tid];
        v6 = p[6 * 256 + tid];
        v7 = p[7 * 256 + tid];
    }

    // ---- Phase 1: collect candidates above a threshold ----------------
    // thr=2.5: E[count]=51 for iid N(0,1) rows; retries are cheap register
    // re-scans (no reload). cand[] fill order is racy; keys are unique so
    // rank-selection below is still exactly deterministic.
    const float thrs[6] = {2.5f, 2.0f, 3.2f, 1.2f, 0.0f, -2.0f};
    bool ok = false;
    int count = 0;

    for (int ti = 0; ti < 6 && !ok; ++ti) {
        const float thr = thrs[ti];
        if (tid == 0) s_count = 0;
        __syncthreads();

        #pragma unroll
        for (int i = 0; i < 8; ++i) {
            const float4 v = (i == 0) ? v0 : (i == 1) ? v1 : (i == 2) ? v2 :
                             (i == 3) ? v3 : (i == 4) ? v4 : (i == 5) ? v5 :
                             (i == 6) ? v6 : v7;
            const int base = (i * 256 + tid) * 4;
            #pragma unroll
            for (int c = 0; c < 4; ++c) {
                const float f = (c == 0) ? v.x : (c == 1) ? v.y :
                                (c == 2) ? v.z : v.w;
                if (f > thr) {
                    const int pos = atomicAdd(&s_count, 1);
                    if (pos < CAP) {
                        const int idx = base + c;
                        cand[pos] = ((unsigned long long)f2key(f) << 32) |
                                    (uint32_t)(~(uint32_t)idx);
                    }
                }
            }
        }
        __syncthreads();
        count = s_count;               // uniform across block
        ok = (count >= k && count <= CAP);
        __syncthreads();               // protect s_count reset next iter
    }

    // ---- Phase 2: rank-based top-k selection (no sort) ----------------
    if (ok) {
        // Each thread owns candidates i = tid, tid+256, ...  rank(i) =
        // #{j : key_j > key_i}; keys unique -> ranks unique -> s_sel writes
        // are race-free and deterministic. cand[j] reads are same-address
        // across lanes -> LDS broadcast, conflict-free.
        #pragma unroll
        for (int m = 0; m < CAP / 256; ++m) {
            const int i = m * 256 + tid;
            if (i < count) {
                const unsigned long long mykey = cand[i];
                int rank = 0;
                for (int j = 0; j < count; ++j)
                    rank += (cand[j] > mykey) ? 1 : 0;
                if (rank < k)
                    s_sel[rank] = (int)(~(uint32_t)(mykey & 0xFFFFFFFFull));
            }
        }
        __syncthreads();
    } else {
        // exact (slow) fallback — never triggers for normal data
        for (int t = 0; t < k; ++t) {
            unsigned long long best = 0ull;
            for (int it = 0; it < NDIM / 256; ++it) {
                const int idx = it * 256 + tid;
                const float f = rowp[idx];
                bool taken = false;
                for (int s = 0; s < t; ++s) taken |= (s_sel[s] == idx);
                if (!taken) {
                    const unsigned long long comp =
                        ((unsigned long long)f2key(f) << 32) |
                        (uint32_t)(~(uint32_t)idx);
                    if (comp > best) best = comp;
                }
            }
            #pragma unroll
            for (int o = 32; o > 0; o >>= 1) {
                const unsigned long long other = __shfl_down(best, o, 64);
                if (other > best) best = other;
            }
            if (lane == 0) s_red[wid] = best;
            __syncthreads();
            if (tid == 0) {
                unsigned long long b = s_red[0];
                for (int w = 1; w < 4; ++w)
                    if (s_red[w] > b) b = s_red[w];
                s_sel[t] = (int)(~(uint32_t)(b & 0xFFFFFFFFull));
            }
            __syncthreads();
        }
    }

    // ---- Phase 3: gather + residual -----------------------------------
    // tid == column d (DDIM == 256 == blockDim.x); each wave's read of a
    // selected X row segment is 256B contiguous -> coalesced, L2-resident.
    float acc = 0.0f;
    for (int t = 0; t < k; ++t) {
        acc += X[(size_t)s_sel[t] * DDIM + tid];
    }
    out[(size_t)row * DDIM + tid] = xres + alpha * acc;
}

extern "C" void kernel_launch(void* const* d_in, const int* in_sizes, int n_in,
                              void* d_out, int out_size, void* d_ws, size_t ws_size,
                              hipStream_t stream) {
    const float* A     = (const float*)d_in[0];
    const float* X     = (const float*)d_in[1];
    const float* alpha = (const float*)d_in[2];
    const int*   k     = (const int*)d_in[3];
    float* out = (float*)d_out;

    topk_agg_kernel<<<NDIM, 256, 0, stream>>>(A, X, alpha, k, out);
}

// Round 4
// 68.055 us; speedup vs baseline: 2.1662x; 1.1186x over previous
//
#include <hip/hip_runtime.h>
#include <stdint.h>

#define NDIM 8192
#define DDIM 256
#define CAP  2048   // candidate capacity (power of 2)
#define MAXK 64

typedef float v4f __attribute__((ext_vector_type(4)));

// Map float bits to an unsigned key with the same total order.
__device__ inline uint32_t f2key(float f) {
    uint32_t u = __float_as_uint(f);
    return (u & 0x80000000u) ? ~u : (u | 0x80000000u);
}

__global__ __launch_bounds__(256) void topk_agg_kernel(
    const float* __restrict__ A, const float* __restrict__ X,
    const float* __restrict__ alpha_p, const int* __restrict__ k_p,
    float* __restrict__ out)
{
    const int row  = blockIdx.x;
    const int tid  = threadIdx.x;
    const int lane = tid & 63;
    const int wid  = tid >> 6;

    __shared__ unsigned long long cand[CAP];
    __shared__ int s_count;
    __shared__ int s_sel[MAXK];
    __shared__ unsigned long long s_red[4];

    int k = *k_p;
    if (k > MAXK) k = MAXK;           // defensive clamp (k==32 here)
    const float alpha = *alpha_p;

    const float* __restrict__ rowp = A + (size_t)row * NDIM;

    // Prefetch the residual X value early (independent of selection).
    const float xres = X[(size_t)row * DDIM + tid];

    // ---- Load the whole row into registers (8 independent float4) ----
    // Non-temporal: A is a read-once stream; don't evict X from L2/L3.
    v4f v0, v1, v2, v3, v4, v5, v6, v7;
    {
        const v4f* p = reinterpret_cast<const v4f*>(rowp);
        v0 = __builtin_nontemporal_load(p + 0 * 256 + tid);
        v1 = __builtin_nontemporal_load(p + 1 * 256 + tid);
        v2 = __builtin_nontemporal_load(p + 2 * 256 + tid);
        v3 = __builtin_nontemporal_load(p + 3 * 256 + tid);
        v4 = __builtin_nontemporal_load(p + 4 * 256 + tid);
        v5 = __builtin_nontemporal_load(p + 5 * 256 + tid);
        v6 = __builtin_nontemporal_load(p + 6 * 256 + tid);
        v7 = __builtin_nontemporal_load(p + 7 * 256 + tid);
    }

    // ---- Phase 1: collect candidates above a threshold ----------------
    // thr=2.45: E[count]~58 for iid N(0,1) rows; P(count<32)~0.02% -> retry
    // is a cheap register re-scan. cand[] fill order is racy; keys unique
    // so rank-selection stays exactly deterministic.
    const float thrs[6] = {2.45f, 2.0f, 3.2f, 1.2f, 0.0f, -2.0f};
    bool ok = false;
    int count = 0;

    for (int ti = 0; ti < 6 && !ok; ++ti) {
        const float thr = thrs[ti];
        if (tid == 0) s_count = 0;
        __syncthreads();

        #pragma unroll
        for (int i = 0; i < 8; ++i) {
            const v4f v = (i == 0) ? v0 : (i == 1) ? v1 : (i == 2) ? v2 :
                          (i == 3) ? v3 : (i == 4) ? v4 : (i == 5) ? v5 :
                          (i == 6) ? v6 : v7;
            const int base = (i * 256 + tid) * 4;
            #pragma unroll
            for (int c = 0; c < 4; ++c) {
                const float f = v[c];
                if (f > thr) {
                    const int pos = atomicAdd(&s_count, 1);
                    if (pos < CAP) {
                        const int idx = base + c;
                        cand[pos] = ((unsigned long long)f2key(f) << 32) |
                                    (uint32_t)(~(uint32_t)idx);
                    }
                }
            }
        }
        __syncthreads();
        count = s_count;               // uniform across block
        ok = (count >= k && count <= CAP);
        __syncthreads();               // protect s_count reset next iter
    }

    // ---- Phase 2: rank-based top-k selection (no sort) ----------------
    if (ok) {
        // rank(i) = #{j : key_j > key_i}; keys unique -> ranks unique ->
        // s_sel writes race-free + deterministic. Inner loop unrolled 8x so
        // 8 independent LDS broadcast reads are in flight (latency /8).
        #pragma unroll
        for (int m = 0; m < CAP / 256; ++m) {
            const int i = m * 256 + tid;
            if (i < count) {
                const unsigned long long mykey = cand[i];
                int rank = 0;
                int j = 0;
                for (; j + 8 <= count; j += 8) {
                    const unsigned long long c0 = cand[j + 0];
                    const unsigned long long c1 = cand[j + 1];
                    const unsigned long long c2 = cand[j + 2];
                    const unsigned long long c3 = cand[j + 3];
                    const unsigned long long c4 = cand[j + 4];
                    const unsigned long long c5 = cand[j + 5];
                    const unsigned long long c6 = cand[j + 6];
                    const unsigned long long c7 = cand[j + 7];
                    rank += (c0 > mykey) + (c1 > mykey) + (c2 > mykey) +
                            (c3 > mykey) + (c4 > mykey) + (c5 > mykey) +
                            (c6 > mykey) + (c7 > mykey);
                }
                for (; j < count; ++j)
                    rank += (cand[j] > mykey) ? 1 : 0;
                if (rank < k)
                    s_sel[rank] = (int)(~(uint32_t)(mykey & 0xFFFFFFFFull));
            }
        }
        __syncthreads();
    } else {
        // exact (slow) fallback — never triggers for normal data
        for (int t = 0; t < k; ++t) {
            unsigned long long best = 0ull;
            for (int it = 0; it < NDIM / 256; ++it) {
                const int idx = it * 256 + tid;
                const float f = rowp[idx];
                bool taken = false;
                for (int s = 0; s < t; ++s) taken |= (s_sel[s] == idx);
                if (!taken) {
                    const unsigned long long comp =
                        ((unsigned long long)f2key(f) << 32) |
                        (uint32_t)(~(uint32_t)idx);
                    if (comp > best) best = comp;
                }
            }
            #pragma unroll
            for (int o = 32; o > 0; o >>= 1) {
                const unsigned long long other = __shfl_down(best, o, 64);
                if (other > best) best = other;
            }
            if (lane == 0) s_red[wid] = best;
            __syncthreads();
            if (tid == 0) {
                unsigned long long b = s_red[0];
                for (int w = 1; w < 4; ++w)
                    if (s_red[w] > b) b = s_red[w];
                s_sel[t] = (int)(~(uint32_t)(b & 0xFFFFFFFFull));
            }
            __syncthreads();
        }
    }

    // ---- Phase 3: gather + residual -----------------------------------
    // tid == column d; per-wave reads of X row segments are 256B contiguous
    // -> coalesced, L2/L3-hot (A used nt loads so X stays resident).
    float acc;
    if (k == 32) {
        // fully unrolled: 4 accumulators, many loads in the vmcnt queue
        float a0 = 0.f, a1 = 0.f, a2 = 0.f, a3 = 0.f;
        #pragma unroll
        for (int t = 0; t < 32; t += 4) {
            const float g0 = X[(size_t)s_sel[t + 0] * DDIM + tid];
            const float g1 = X[(size_t)s_sel[t + 1] * DDIM + tid];
            const float g2 = X[(size_t)s_sel[t + 2] * DDIM + tid];
            const float g3 = X[(size_t)s_sel[t + 3] * DDIM + tid];
            a0 += g0; a1 += g1; a2 += g2; a3 += g3;
        }
        acc = (a0 + a1) + (a2 + a3);
    } else {
        acc = 0.f;
        for (int t = 0; t < k; ++t)
            acc += X[(size_t)s_sel[t] * DDIM + tid];
    }
    __builtin_nontemporal_store(xres + alpha * acc,
                                out + (size_t)row * DDIM + tid);
}

extern "C" void kernel_launch(void* const* d_in, const int* in_sizes, int n_in,
                              void* d_out, int out_size, void* d_ws, size_t ws_size,
                              hipStream_t stream) {
    const float* A     = (const float*)d_in[0];
    const float* X     = (const float*)d_in[1];
    const float* alpha = (const float*)d_in[2];
    const int*   k     = (const int*)d_in[3];
    float* out = (float*)d_out;

    topk_agg_kernel<<<NDIM, 256, 0, stream>>>(A, X, alpha, k, out);
}

// Round 5
// 67.882 us; speedup vs baseline: 2.1717x; 1.0026x over previous
//
#include <hip/hip_runtime.h>
#include <stdint.h>

#define NDIM 8192
#define DDIM 256
#define CAP  256    // candidate capacity (power of 2) — small to keep LDS tiny
#define MAXK 64

typedef float v4f __attribute__((ext_vector_type(4)));

// Map float bits to an unsigned key with the same total order.
__device__ inline uint32_t f2key(float f) {
    uint32_t u = __float_as_uint(f);
    return (u & 0x80000000u) ? ~u : (u | 0x80000000u);
}

__global__ __launch_bounds__(256) void topk_agg_kernel(
    const float* __restrict__ A, const float* __restrict__ X,
    const float* __restrict__ alpha_p, const int* __restrict__ k_p,
    float* __restrict__ out)
{
    const int row  = blockIdx.x;
    const int tid  = threadIdx.x;
    const int lane = tid & 63;
    const int wid  = tid >> 6;

    // Total LDS ~2.6 KB -> occupancy is VGPR-limited (~8 blocks/CU), not LDS.
    __shared__ unsigned long long cand[CAP];
    __shared__ int s_count;
    __shared__ int s_sel[MAXK];
    __shared__ unsigned long long s_red[4];

    int k = *k_p;
    if (k > MAXK) k = MAXK;           // defensive clamp (k==32 here)
    const float alpha = *alpha_p;

    const float* __restrict__ rowp = A + (size_t)row * NDIM;

    // Prefetch the residual X value early (independent of selection).
    const float xres = X[(size_t)row * DDIM + tid];

    // ---- Load the whole row into registers (8 independent float4) ----
    // Non-temporal: A is a read-once stream; don't evict X from L2/L3.
    v4f v0, v1, v2, v3, v4, v5, v6, v7;
    {
        const v4f* p = reinterpret_cast<const v4f*>(rowp);
        v0 = __builtin_nontemporal_load(p + 0 * 256 + tid);
        v1 = __builtin_nontemporal_load(p + 1 * 256 + tid);
        v2 = __builtin_nontemporal_load(p + 2 * 256 + tid);
        v3 = __builtin_nontemporal_load(p + 3 * 256 + tid);
        v4 = __builtin_nontemporal_load(p + 4 * 256 + tid);
        v5 = __builtin_nontemporal_load(p + 5 * 256 + tid);
        v6 = __builtin_nontemporal_load(p + 6 * 256 + tid);
        v7 = __builtin_nontemporal_load(p + 7 * 256 + tid);
    }

    // ---- Phase 1: collect candidates above a threshold ----------------
    // thr=2.45: count ~ Bin(8192, 0.00714), E=58, sigma=7.6.
    //   P(count<32) ~ 2e-4 -> cheap register re-scan at 2.0.
    //   P(count>256) at 2.0 (E=186, sigma=13.5) ~ 5sigma -> safe; further
    //   retries + exact fallback guarantee correctness for any data.
    const float thrs[6] = {2.45f, 2.0f, 3.2f, 1.2f, 0.0f, -2.0f};
    bool ok = false;
    int count = 0;

    for (int ti = 0; ti < 6 && !ok; ++ti) {
        const float thr = thrs[ti];
        if (tid == 0) s_count = 0;
        __syncthreads();

        #pragma unroll
        for (int i = 0; i < 8; ++i) {
            const v4f v = (i == 0) ? v0 : (i == 1) ? v1 : (i == 2) ? v2 :
                          (i == 3) ? v3 : (i == 4) ? v4 : (i == 5) ? v5 :
                          (i == 6) ? v6 : v7;
            const int base = (i * 256 + tid) * 4;
            #pragma unroll
            for (int c = 0; c < 4; ++c) {
                const float f = v[c];
                if (f > thr) {
                    const int pos = atomicAdd(&s_count, 1);
                    if (pos < CAP) {
                        const int idx = base + c;
                        cand[pos] = ((unsigned long long)f2key(f) << 32) |
                                    (uint32_t)(~(uint32_t)idx);
                    }
                }
            }
        }
        __syncthreads();
        count = s_count;               // uniform across block
        ok = (count >= k && count <= CAP);
        __syncthreads();               // protect s_count reset next iter
    }

    // ---- Phase 2: rank-based top-k selection (no sort) ----------------
    if (ok) {
        // rank(i) = #{j : key_j > key_i}; keys unique -> ranks unique ->
        // s_sel writes race-free + deterministic. Inner loop unrolled 8x so
        // 8 independent LDS broadcast reads are in flight.
        if (tid < count) {
            const unsigned long long mykey = cand[tid];
            int rank = 0;
            int j = 0;
            for (; j + 8 <= count; j += 8) {
                const unsigned long long c0 = cand[j + 0];
                const unsigned long long c1 = cand[j + 1];
                const unsigned long long c2 = cand[j + 2];
                const unsigned long long c3 = cand[j + 3];
                const unsigned long long c4 = cand[j + 4];
                const unsigned long long c5 = cand[j + 5];
                const unsigned long long c6 = cand[j + 6];
                const unsigned long long c7 = cand[j + 7];
                rank += (c0 > mykey) + (c1 > mykey) + (c2 > mykey) +
                        (c3 > mykey) + (c4 > mykey) + (c5 > mykey) +
                        (c6 > mykey) + (c7 > mykey);
            }
            for (; j < count; ++j)
                rank += (cand[j] > mykey) ? 1 : 0;
            if (rank < k)
                s_sel[rank] = (int)(~(uint32_t)(mykey & 0xFFFFFFFFull));
        }
        __syncthreads();
    } else {
        // exact (slow) fallback — never triggers for normal data
        for (int t = 0; t < k; ++t) {
            unsigned long long best = 0ull;
            for (int it = 0; it < NDIM / 256; ++it) {
                const int idx = it * 256 + tid;
                const float f = rowp[idx];
                bool taken = false;
                for (int s = 0; s < t; ++s) taken |= (s_sel[s] == idx);
                if (!taken) {
                    const unsigned long long comp =
                        ((unsigned long long)f2key(f) << 32) |
                        (uint32_t)(~(uint32_t)idx);
                    if (comp > best) best = comp;
                }
            }
            #pragma unroll
            for (int o = 32; o > 0; o >>= 1) {
                const unsigned long long other = __shfl_down(best, o, 64);
                if (other > best) best = other;
            }
            if (lane == 0) s_red[wid] = best;
            __syncthreads();
            if (tid == 0) {
                unsigned long long b = s_red[0];
                for (int w = 1; w < 4; ++w)
                    if (s_red[w] > b) b = s_red[w];
                s_sel[t] = (int)(~(uint32_t)(b & 0xFFFFFFFFull));
            }
            __syncthreads();
        }
    }

    // ---- Phase 3: gather + residual -----------------------------------
    // tid == column d; per-wave reads of X row segments are 256B contiguous
    // -> coalesced, L2/L3-hot (A used nt loads so X stays resident).
    float acc;
    if (k == 32) {
        // fully unrolled: 4 accumulators, many loads in the vmcnt queue
        float a0 = 0.f, a1 = 0.f, a2 = 0.f, a3 = 0.f;
        #pragma unroll
        for (int t = 0; t < 32; t += 4) {
            const float g0 = X[(size_t)s_sel[t + 0] * DDIM + tid];
            const float g1 = X[(size_t)s_sel[t + 1] * DDIM + tid];
            const float g2 = X[(size_t)s_sel[t + 2] * DDIM + tid];
            const float g3 = X[(size_t)s_sel[t + 3] * DDIM + tid];
            a0 += g0; a1 += g1; a2 += g2; a3 += g3;
        }
        acc = (a0 + a1) + (a2 + a3);
    } else {
        acc = 0.f;
        for (int t = 0; t < k; ++t)
            acc += X[(size_t)s_sel[t] * DDIM + tid];
    }
    __builtin_nontemporal_store(xres + alpha * acc,
                                out + (size_t)row * DDIM + tid);
}

extern "C" void kernel_launch(void* const* d_in, const int* in_sizes, int n_in,
                              void* d_out, int out_size, void* d_ws, size_t ws_size,
                              hipStream_t stream) {
    const float* A     = (const float*)d_in[0];
    const float* X     = (const float*)d_in[1];
    const float* alpha = (const float*)d_in[2];
    const int*   k     = (const int*)d_in[3];
    float* out = (float*)d_out;

    topk_agg_kernel<<<NDIM, 256, 0, stream>>>(A, X, alpha, k, out);
}